// Round 4
// baseline (603.328 us; speedup 1.0000x reference)
//
#include <hip/hip_runtime.h>

// Problem constants
#define BATCH 64
#define CH    256
#define HW    4096
#define TOK   256
#define ITERS 30

// k2 = (dot - 1) * 1/(eps*ln2);  eps = 0.05.  E = 2^k2 = exp(-cost/eps).
constexpr float K2SCALE   = 28.853900817779268f;    // 1/(0.05*ln2)
constexpr float LOSSSCALE = -0.034657359027997264f; // -0.05*ln2  (cost = LOSSSCALE*k2)

// ws layout in floats
#define TOKP_OFF 0
#define TOKT_OFF (BATCH*CH*TOK)               // 4,194,304
#define K2_OFF   (2*BATCH*CH*TOK)             // 8,388,608
#define LOSS_OFF (K2_OFF + BATCH*TOK*TOK)     // 12,582,912
// total 12,582,976 floats = 50.3 MB

// HIP has no __exp2f fast intrinsic (CUDA-only); glibc's math.h reserves the
// name -> round-3 compile failure. Use the amdgcn builtins that map 1:1 to
// v_exp_f32 (2^x) / v_log_f32 (log2 x), with ocml fallback.
__device__ __forceinline__ float fexp2(float x) {
#if __has_builtin(__builtin_amdgcn_exp2f)
    return __builtin_amdgcn_exp2f(x);
#else
    return exp2f(x);
#endif
}
__device__ __forceinline__ float flog2(float x) {
#if __has_builtin(__builtin_amdgcn_logf)
    return __builtin_amdgcn_logf(x);   // v_log_f32: log2(x)
#else
    return log2f(x);
#endif
}

__device__ __forceinline__ int sample_pos(int i) {
    // mimic jnp.linspace(0, 4095, 256).astype(int32): fp32 step = RN(4095/255),
    // fp32 mul, truncate.  Safety: multiples of 17 land within 1e-6 of the exact
    // integer and round back to it (ulp margin); non-multiples sit >=1/17 from
    // any integer vs <=2.5e-4 product error -> no truncation flips.
    const float step = 4095.0f / 255.0f;
    return (int)((float)i * step);
}

// ---------------------------------------------------------------------------
// K1: gather sampled tokens into [b][c][i] layout (i fast -> coalesced writes)
// grid 1024 = b(64) x tensor(2) x cchunk(8);  block 256 (one thread per token)
// Sampled positions are ~64B apart -> every 64B line of the 512MB input is
// touched exactly once: full-input fetch is forced, this kernel IS the floor.
// ---------------------------------------------------------------------------
__global__ __launch_bounds__(256) void gather_kernel(
        const float* __restrict__ pred, const float* __restrict__ targ,
        float* __restrict__ ws) {
    int bx = blockIdx.x;
    int b  = bx >> 4;
    int t  = (bx >> 3) & 1;
    int ch = bx & 7;
    int i  = threadIdx.x;
    int pos = sample_pos(i);

    const float* src = t ? targ : pred;
    float* dst = ws + (t ? TOKT_OFF : TOKP_OFF);

    size_t sbase = (size_t)b * CH * HW + (size_t)pos;
    size_t dbase = (size_t)b * CH * TOK + (size_t)i;
    int c0 = ch * 32;
#pragma unroll 16
    for (int cc = 0; cc < 32; ++cc) {
        int c = c0 + cc;
        dst[dbase + (size_t)c * TOK] = src[sbase + (size_t)c * HW];
    }
}

// ---------------------------------------------------------------------------
// K2: per-batch 256x256x256 fp32 GEMM -> k2 = (p.t/(|p||t|) - 1)*K2SCALE,
// with per-token L2 norms FUSED into the staging loop (no separate norm pass):
// col = (q*256+tid)&127 == tid&127 is constant per thread, so each thread sees
// one A-column and one B-column; tid and tid^128 together cover all 256
// channels (even/odd cc).  Norm reduce: one LDS exchange + rsqrt.
// grid 256 = b(64) x 4 tiles(128x128); block 256 (16x16 threads, 8x8 each)
// ---------------------------------------------------------------------------
__global__ __launch_bounds__(256) void gemm_kernel(float* __restrict__ ws) {
    __shared__ float at[32][132];   // +4 pad: rows stay 16B aligned
    __shared__ float bt[32][132];
    __shared__ float rnA[128];      // per-column partials, then 1/max(|p|,1e-12)
    __shared__ float rnB[128];

    int bx = blockIdx.x;
    int b = bx >> 2, tile = bx & 3;
    int i0 = (tile >> 1) * 128;
    int j0 = (tile & 1) * 128;
    int tid = threadIdx.x;
    int tx = tid & 15, ty = tid >> 4;

    const float* tp = ws + TOKP_OFF + (size_t)b * CH * TOK;
    const float* tt = ws + TOKT_OFF + (size_t)b * CH * TOK;

    float acc[8][8] = {};
    float sa = 0.0f, sb = 0.0f;     // sum of squares for my A-col / B-col

    for (int chnk = 0; chnk < 8; ++chnk) {
#pragma unroll
        for (int q = 0; q < 16; ++q) {
            int idx = q * 256 + tid;
            int cc = idx >> 7, col = idx & 127;
            float va = tp[(size_t)(chnk * 32 + cc) * TOK + i0 + col];
            float vb = tt[(size_t)(chnk * 32 + cc) * TOK + j0 + col];
            at[cc][col] = va;
            bt[cc][col] = vb;
            sa = fmaf(va, va, sa);
            sb = fmaf(vb, vb, sb);
        }
        __syncthreads();
#pragma unroll
        for (int cc = 0; cc < 32; ++cc) {
            float4 a0 = *(const float4*)&at[cc][tx * 8];
            float4 a1 = *(const float4*)&at[cc][tx * 8 + 4];
            float4 b0 = *(const float4*)&bt[cc][ty * 8];
            float4 b1 = *(const float4*)&bt[cc][ty * 8 + 4];
            float af[8] = {a0.x, a0.y, a0.z, a0.w, a1.x, a1.y, a1.z, a1.w};
            float bf[8] = {b0.x, b0.y, b0.z, b0.w, b1.x, b1.y, b1.z, b1.w};
#pragma unroll
            for (int r = 0; r < 8; ++r)
#pragma unroll
                for (int c = 0; c < 8; ++c)
                    acc[r][c] = fmaf(af[r], bf[c], acc[r][c]);
        }
        __syncthreads();
    }

    // combine the two half-channel partials (tid <-> tid^128), make 1/norm
    if (tid >= 128) { rnA[tid - 128] = sa; rnB[tid - 128] = sb; }
    __syncthreads();
    if (tid < 128) {
        float fa = sa + rnA[tid];
        float fb = sb + rnB[tid];
        rnA[tid] = 1.0f / fmaxf(sqrtf(fa), 1e-12f);
        rnB[tid] = 1.0f / fmaxf(sqrtf(fb), 1e-12f);
    }
    __syncthreads();

    float rpf[8], rtf[8];
#pragma unroll
    for (int r = 0; r < 8; ++r) rpf[r] = rnA[tx * 8 + r];
#pragma unroll
    for (int c = 0; c < 8; ++c) rtf[c] = rnB[ty * 8 + c];

    float* K2w = ws + K2_OFF + (size_t)b * TOK * TOK;
#pragma unroll
    for (int r = 0; r < 8; ++r) {
        float out[8];
#pragma unroll
        for (int c = 0; c < 8; ++c)
            out[c] = (acc[r][c] * rpf[r] * rtf[c] - 1.0f) * K2SCALE;
        size_t row = (size_t)(i0 + tx * 8 + r) * TOK + j0 + ty * 8;
        *(float4*)&K2w[row]     = make_float4(out[0], out[1], out[2], out[3]);
        *(float4*)&K2w[row + 4] = make_float4(out[4], out[5], out[6], out[7]);
    }
}

// ---------------------------------------------------------------------------
// K3: Sinkhorn with E = 2^k2 precomputed in registers (8x8/thread).
// ZERO transcendentals in the 60-phase loop:
//   wu[i] = 2^u[i] = 2^-8 / (sum_j E[i][j]*wv[j])   (pure FMA matvec + rcp)
// grid 64 (one block per batch); block 1024 (ti=tid>>5 rows, tj=tid&31 cols).
// Reduce layout red[pos][lane], 33-float rows: all LDS ops <=2-way (free).
// wuperm[ti+32r] = WU[8ti+r]; wvperm[tj+32c] = WV[8tj+c] (permuted storage:
// broadcast reads on the consume side, conflict-free on the write side).
// Range: E in [2^-58, 1], wu,wv <= ~2^41 transiently, sums fp32-normal -> safe.
// ---------------------------------------------------------------------------
__global__ __launch_bounds__(1024, 1) void sinkhorn_kernel(float* __restrict__ ws) {
    __shared__ float red[256][33];
    __shared__ float wuperm[256];
    __shared__ float wvperm[256];
    __shared__ float wsum[16];

    int b = blockIdx.x;
    int tid = threadIdx.x;
    int ti = tid >> 5, tj = tid & 31;

    const float* K2r = ws + K2_OFF + (size_t)b * TOK * TOK;
    float e[8][8];
#pragma unroll
    for (int r = 0; r < 8; ++r) {
        const float4* p = (const float4*)&K2r[(size_t)(8 * ti + r) * TOK + 8 * tj];
        float4 v0 = p[0], v1 = p[1];
        e[r][0] = fexp2(v0.x); e[r][1] = fexp2(v0.y);
        e[r][2] = fexp2(v0.z); e[r][3] = fexp2(v0.w);
        e[r][4] = fexp2(v1.x); e[r][5] = fexp2(v1.y);
        e[r][6] = fexp2(v1.z); e[r][7] = fexp2(v1.w);
    }

    if (tid < 256) wvperm[tid] = 1.0f;   // wv = 2^0
    __syncthreads();

    for (int it = 0; it < ITERS; ++it) {
        // ---- u-phase: wu[i] = 2^-8 / sum_j E[i][j]*wv[j]
        float wv[8];
#pragma unroll
        for (int c = 0; c < 8; ++c) wv[c] = wvperm[tj + 32 * c];
#pragma unroll
        for (int r = 0; r < 8; ++r) {
            float s = 0.0f;
#pragma unroll
            for (int c = 0; c < 8; ++c) s = fmaf(e[r][c], wv[c], s);
            red[ti + 32 * r][tj] = s;   // bank = (ti+tj)%32 -> 2-way, free
        }
        __syncthreads();
        if (tid < 256) {
            float s = 0.0f;
#pragma unroll
            for (int q = 0; q < 32; ++q) s += red[tid][q];  // (tid+q)%32 -> 2-way
            wuperm[tid] = 0.00390625f / s;
        }
        __syncthreads();

        // ---- v-phase: wv[j] = 2^-8 / sum_i E[i][j]*wu[i]
        float wu[8];
#pragma unroll
        for (int r = 0; r < 8; ++r) wu[r] = wuperm[ti + 32 * r];  // broadcast
#pragma unroll
        for (int c = 0; c < 8; ++c) {
            float s = 0.0f;
#pragma unroll
            for (int r = 0; r < 8; ++r) s = fmaf(e[r][c], wu[r], s);
            red[tj + 32 * c][ti] = s;   // 2-way, free
        }
        __syncthreads();
        if (tid < 256) {
            float s = 0.0f;
#pragma unroll
            for (int q = 0; q < 32; ++q) s += red[tid][q];
            wvperm[tid] = 0.00390625f / s;
        }
        __syncthreads();
    }

    // ---- loss: transport = E*wu*wv; cost = LOSSSCALE*k2, k2 = log2(E)
    float wu[8], wv[8];
#pragma unroll
    for (int r = 0; r < 8; ++r) wu[r] = wuperm[ti + 32 * r];
#pragma unroll
    for (int c = 0; c < 8; ++c) wv[c] = wvperm[tj + 32 * c];

    float acc = 0.0f;
#pragma unroll
    for (int r = 0; r < 8; ++r)
#pragma unroll
        for (int c = 0; c < 8; ++c)
            acc += e[r][c] * wu[r] * wv[c] * flog2(e[r][c]);

#pragma unroll
    for (int off = 32; off >= 1; off >>= 1) acc += __shfl_xor(acc, off, 64);
    int wid = tid >> 6, lane = tid & 63;
    if (lane == 0) wsum[wid] = acc;
    __syncthreads();
    if (tid == 0) {
        float s = 0.0f;
#pragma unroll
        for (int w = 0; w < 16; ++w) s += wsum[w];
        ws[LOSS_OFF + b] = s * LOSSSCALE;
    }
}

// ---------------------------------------------------------------------------
// K4: mean over 64 batch losses
// ---------------------------------------------------------------------------
__global__ __launch_bounds__(64) void final_kernel(const float* __restrict__ ws,
                                                   float* __restrict__ out) {
    int tid = threadIdx.x;
    float v = ws[LOSS_OFF + tid];
#pragma unroll
    for (int off = 32; off >= 1; off >>= 1) v += __shfl_xor(v, off, 64);
    if (tid == 0) out[0] = v * (1.0f / 64.0f);
}

extern "C" void kernel_launch(void* const* d_in, const int* in_sizes, int n_in,
                              void* d_out, int out_size, void* d_ws, size_t ws_size,
                              hipStream_t stream) {
    const float* pred = (const float*)d_in[0];
    const float* targ = (const float*)d_in[1];
    float* ws = (float*)d_ws;
    float* out = (float*)d_out;

    hipLaunchKernelGGL(gather_kernel,   dim3(1024), dim3(256),  0, stream, pred, targ, ws);
    hipLaunchKernelGGL(gemm_kernel,     dim3(256),  dim3(256),  0, stream, ws);
    hipLaunchKernelGGL(sinkhorn_kernel, dim3(64),   dim3(1024), 0, stream, ws);
    hipLaunchKernelGGL(final_kernel,    dim3(1),    dim3(64),   0, stream, ws, out);
}

// Round 5
// 603.003 us; speedup vs baseline: 1.0005x; 1.0005x over previous
//
#include <hip/hip_runtime.h>

// Problem constants
#define BATCH 64
#define CH    256
#define HW    4096
#define TOK   256
#define ITERS 30

// k2 = (dot - 1) * 1/(eps*ln2);  eps = 0.05.  E = 2^k2 = exp(-cost/eps).
constexpr float K2SCALE   = 28.853900817779268f;    // 1/(0.05*ln2)
constexpr float LOSSSCALE = -0.034657359027997264f; // -0.05*ln2  (cost = LOSSSCALE*k2)

// ws layout in floats
#define TOKP_OFF 0
#define TOKT_OFF (BATCH*CH*TOK)               // 4,194,304
#define K2_OFF   (2*BATCH*CH*TOK)             // 8,388,608
#define LOSS_OFF (K2_OFF + BATCH*TOK*TOK)     // 12,582,912
// total 12,582,976 floats = 50.3 MB

// HIP has no __exp2f fast intrinsic; use amdgcn builtins (v_exp_f32 = 2^x,
// v_log_f32 = log2 x) with ocml fallback.  (round-3 lesson)
__device__ __forceinline__ float fexp2(float x) {
#if __has_builtin(__builtin_amdgcn_exp2f)
    return __builtin_amdgcn_exp2f(x);
#else
    return exp2f(x);
#endif
}
__device__ __forceinline__ float flog2(float x) {
#if __has_builtin(__builtin_amdgcn_logf)
    return __builtin_amdgcn_logf(x);   // v_log_f32: log2(x)
#else
    return log2f(x);
#endif
}

__device__ __forceinline__ int sample_pos(int i) {
    // mimic jnp.linspace(0, 4095, 256).astype(int32): fp32 step = RN(4095/255),
    // fp32 mul, truncate.  No truncation flips (1/17 margin vs 2.5e-4 error).
    const float step = 4095.0f / 255.0f;
    return (int)((float)i * step);
}

// ---------------------------------------------------------------------------
// K1: gather sampled tokens into [b][c][i] layout (i fast -> coalesced writes)
// grid 4096 = b(64) x tensor(2) x cchunk(32);  block 256 (one thread/token).
// R4 counters: 160us @ 1.88 TB/s, VALUBusy 0.3% -> latency/miss-parallelism
// bound, NOT BW bound.  Fixes: (a) 8 blocks/CU (32 waves/CU, was 16),
// (b) all 8 loads issued into registers BEFORE any store (was interleaved,
// which serialized on store->load waitcnts).  Lines are contiguous per wave
// (line(i) == i), so DRAM efficiency is ideal given enough outstanding misses.
// ---------------------------------------------------------------------------
__global__ __launch_bounds__(256) void gather_kernel(
        const float* __restrict__ pred, const float* __restrict__ targ,
        float* __restrict__ ws) {
    int bx = blockIdx.x;
    int b  = bx >> 6;
    int t  = (bx >> 5) & 1;
    int ch = bx & 31;          // 8 channels per block
    int i  = threadIdx.x;
    int pos = sample_pos(i);

    const float* src = (t ? targ : pred)
                     + (size_t)b * CH * HW + (size_t)(ch * 8) * HW + pos;
    float* dst = ws + (t ? TOKT_OFF : TOKP_OFF)
                    + (size_t)b * CH * TOK + (size_t)(ch * 8) * TOK + i;

    float v[8];
#pragma unroll
    for (int cc = 0; cc < 8; ++cc) v[cc] = src[(size_t)cc * HW];
#pragma unroll
    for (int cc = 0; cc < 8; ++cc) dst[(size_t)cc * TOK] = v[cc];
}

// ---------------------------------------------------------------------------
// K2: per-batch 256x256x256 fp32 GEMM -> k2 = (p.t/(|p||t|) - 1)*K2SCALE,
// per-token L2 norms fused into staging (col = tid&127 is constant/thread;
// tid and tid^128 cover even/odd channels -> one LDS exchange + rsqrt).
// grid 256 = b(64) x 4 tiles(128x128); block 256.
// R5 fragment fix: old at[cc][tx*8] float4-pairs hit banks {0,8,16,24} only
// (4-way conflict, half the banks idle).  New split-fragment reads at stride
// 16B span all 32 banks 2-way (free): rows R(r)=4tx+(r&3)+64*(r>>2), cols
// C(c)=4ty+(c&3)+64*(c>>2).  Pure index permutation; epilogue remapped.
// ---------------------------------------------------------------------------
__global__ __launch_bounds__(256) void gemm_kernel(float* __restrict__ ws) {
    __shared__ float at[32][132];   // +4 pad keeps rows 16B aligned
    __shared__ float bt[32][132];
    __shared__ float rnA[128];
    __shared__ float rnB[128];

    int bx = blockIdx.x;
    int b = bx >> 2, tile = bx & 3;
    int i0 = (tile >> 1) * 128;
    int j0 = (tile & 1) * 128;
    int tid = threadIdx.x;
    int tx = tid & 15, ty = tid >> 4;

    const float* tp = ws + TOKP_OFF + (size_t)b * CH * TOK;
    const float* tt = ws + TOKT_OFF + (size_t)b * CH * TOK;

    float acc[8][8] = {};
    float sa = 0.0f, sb = 0.0f;

    for (int chnk = 0; chnk < 8; ++chnk) {
#pragma unroll
        for (int q = 0; q < 16; ++q) {
            int idx = q * 256 + tid;
            int cc = idx >> 7, col = idx & 127;
            float va = tp[(size_t)(chnk * 32 + cc) * TOK + i0 + col];
            float vb = tt[(size_t)(chnk * 32 + cc) * TOK + j0 + col];
            at[cc][col] = va;
            bt[cc][col] = vb;
            sa = fmaf(va, va, sa);
            sb = fmaf(vb, vb, sb);
        }
        __syncthreads();
#pragma unroll
        for (int cc = 0; cc < 32; ++cc) {
            float4 a0 = *(const float4*)&at[cc][tx * 4];        // rows 4tx..+3
            float4 a1 = *(const float4*)&at[cc][64 + tx * 4];   // rows 64+4tx..+3
            float4 b0 = *(const float4*)&bt[cc][ty * 4];
            float4 b1 = *(const float4*)&bt[cc][64 + ty * 4];
            float af[8] = {a0.x, a0.y, a0.z, a0.w, a1.x, a1.y, a1.z, a1.w};
            float bf[8] = {b0.x, b0.y, b0.z, b0.w, b1.x, b1.y, b1.z, b1.w};
#pragma unroll
            for (int r = 0; r < 8; ++r)
#pragma unroll
                for (int c = 0; c < 8; ++c)
                    acc[r][c] = fmaf(af[r], bf[c], acc[r][c]);
        }
        __syncthreads();
    }

    // combine half-channel norm partials (tid <-> tid^128), make 1/norm
    if (tid >= 128) { rnA[tid - 128] = sa; rnB[tid - 128] = sb; }
    __syncthreads();
    if (tid < 128) {
        float fa = sa + rnA[tid];
        float fb = sb + rnB[tid];
        rnA[tid] = 1.0f / fmaxf(sqrtf(fa), 1e-12f);
        rnB[tid] = 1.0f / fmaxf(sqrtf(fb), 1e-12f);
    }
    __syncthreads();

    float rpf[8], rtf[8];
#pragma unroll
    for (int r = 0; r < 8; ++r) rpf[r] = rnA[4 * tx + (r & 3) + 64 * (r >> 2)];
#pragma unroll
    for (int c = 0; c < 8; ++c) rtf[c] = rnB[4 * ty + (c & 3) + 64 * (c >> 2)];

    float* K2w = ws + K2_OFF + (size_t)b * TOK * TOK;
#pragma unroll
    for (int r = 0; r < 8; ++r) {
        float out[8];
#pragma unroll
        for (int c = 0; c < 8; ++c)
            out[c] = (acc[r][c] * rpf[r] * rtf[c] - 1.0f) * K2SCALE;
        size_t row = (size_t)(i0 + 4 * tx + (r & 3) + 64 * (r >> 2)) * TOK;
        *(float4*)&K2w[row + j0 + 4 * ty]      = make_float4(out[0], out[1], out[2], out[3]);
        *(float4*)&K2w[row + j0 + 64 + 4 * ty] = make_float4(out[4], out[5], out[6], out[7]);
    }
}

// ---------------------------------------------------------------------------
// K3: Sinkhorn with E = 2^k2 precomputed in registers (8x8/thread).
// ZERO transcendentals in the 60-phase loop:
//   wu[i] = 2^u[i] = 2^-8 / (sum_j E[i][j]*wv[j])   (pure FMA matvec + rcp)
// grid 64 (one block per batch); block 1024 (ti=tid>>5 rows, tj=tid&31 cols).
// Reduce layout red[pos][lane], 33-float rows: all LDS ops <=2-way (free).
// ---------------------------------------------------------------------------
__global__ __launch_bounds__(1024, 1) void sinkhorn_kernel(float* __restrict__ ws) {
    __shared__ float red[256][33];
    __shared__ float wuperm[256];
    __shared__ float wvperm[256];
    __shared__ float wsum[16];

    int b = blockIdx.x;
    int tid = threadIdx.x;
    int ti = tid >> 5, tj = tid & 31;

    const float* K2r = ws + K2_OFF + (size_t)b * TOK * TOK;
    float e[8][8];
#pragma unroll
    for (int r = 0; r < 8; ++r) {
        const float4* p = (const float4*)&K2r[(size_t)(8 * ti + r) * TOK + 8 * tj];
        float4 v0 = p[0], v1 = p[1];
        e[r][0] = fexp2(v0.x); e[r][1] = fexp2(v0.y);
        e[r][2] = fexp2(v0.z); e[r][3] = fexp2(v0.w);
        e[r][4] = fexp2(v1.x); e[r][5] = fexp2(v1.y);
        e[r][6] = fexp2(v1.z); e[r][7] = fexp2(v1.w);
    }

    if (tid < 256) wvperm[tid] = 1.0f;   // wv = 2^0
    __syncthreads();

    for (int it = 0; it < ITERS; ++it) {
        // ---- u-phase: wu[i] = 2^-8 / sum_j E[i][j]*wv[j]
        float wv[8];
#pragma unroll
        for (int c = 0; c < 8; ++c) wv[c] = wvperm[tj + 32 * c];
#pragma unroll
        for (int r = 0; r < 8; ++r) {
            float s = 0.0f;
#pragma unroll
            for (int c = 0; c < 8; ++c) s = fmaf(e[r][c], wv[c], s);
            red[ti + 32 * r][tj] = s;   // bank = (ti+tj)%32 -> 2-way, free
        }
        __syncthreads();
        if (tid < 256) {
            float s = 0.0f;
#pragma unroll
            for (int q = 0; q < 32; ++q) s += red[tid][q];  // (tid+q)%32 -> 2-way
            wuperm[tid] = 0.00390625f / s;
        }
        __syncthreads();

        // ---- v-phase: wv[j] = 2^-8 / sum_i E[i][j]*wu[i]
        float wu[8];
#pragma unroll
        for (int r = 0; r < 8; ++r) wu[r] = wuperm[ti + 32 * r];  // broadcast
#pragma unroll
        for (int c = 0; c < 8; ++c) {
            float s = 0.0f;
#pragma unroll
            for (int r = 0; r < 8; ++r) s = fmaf(e[r][c], wu[r], s);
            red[tj + 32 * c][ti] = s;   // 2-way, free
        }
        __syncthreads();
        if (tid < 256) {
            float s = 0.0f;
#pragma unroll
            for (int q = 0; q < 32; ++q) s += red[tid][q];
            wvperm[tid] = 0.00390625f / s;
        }
        __syncthreads();
    }

    // ---- loss: transport = E*wu*wv; cost = LOSSSCALE*k2, k2 = log2(E)
    float wu[8], wv[8];
#pragma unroll
    for (int r = 0; r < 8; ++r) wu[r] = wuperm[ti + 32 * r];
#pragma unroll
    for (int c = 0; c < 8; ++c) wv[c] = wvperm[tj + 32 * c];

    float acc = 0.0f;
#pragma unroll
    for (int r = 0; r < 8; ++r)
#pragma unroll
        for (int c = 0; c < 8; ++c)
            acc += e[r][c] * wu[r] * wv[c] * flog2(e[r][c]);

#pragma unroll
    for (int off = 32; off >= 1; off >>= 1) acc += __shfl_xor(acc, off, 64);
    int wid = tid >> 6, lane = tid & 63;
    if (lane == 0) wsum[wid] = acc;
    __syncthreads();
    if (tid == 0) {
        float s = 0.0f;
#pragma unroll
        for (int w = 0; w < 16; ++w) s += wsum[w];
        ws[LOSS_OFF + b] = s * LOSSSCALE;
    }
}

// ---------------------------------------------------------------------------
// K4: mean over 64 batch losses
// ---------------------------------------------------------------------------
__global__ __launch_bounds__(64) void final_kernel(const float* __restrict__ ws,
                                                   float* __restrict__ out) {
    int tid = threadIdx.x;
    float v = ws[LOSS_OFF + tid];
#pragma unroll
    for (int off = 32; off >= 1; off >>= 1) v += __shfl_xor(v, off, 64);
    if (tid == 0) out[0] = v * (1.0f / 64.0f);
}

extern "C" void kernel_launch(void* const* d_in, const int* in_sizes, int n_in,
                              void* d_out, int out_size, void* d_ws, size_t ws_size,
                              hipStream_t stream) {
    const float* pred = (const float*)d_in[0];
    const float* targ = (const float*)d_in[1];
    float* ws = (float*)d_ws;
    float* out = (float*)d_out;

    hipLaunchKernelGGL(gather_kernel,   dim3(4096), dim3(256),  0, stream, pred, targ, ws);
    hipLaunchKernelGGL(gemm_kernel,     dim3(256),  dim3(256),  0, stream, ws);
    hipLaunchKernelGGL(sinkhorn_kernel, dim3(64),   dim3(1024), 0, stream, ws);
    hipLaunchKernelGGL(final_kernel,    dim3(1),    dim3(64),   0, stream, ws, out);
}